// Round 13
// baseline (4168.519 us; speedup 1.0000x reference)
//
#include <hip/hip_runtime.h>
#include <cstddef>

#define DM    1024
#define DI    2048
#define NSTATE 16
#define LSEQ  2048
// Chunked processing: CB batches per chunk (CB chosen on host from ws_size).
// Chunk = CB*2048 rows. Pass 0 = forward, pass 1 = reverse (reverse kept in
// UNFLIPPED coordinates; only conv taps + scan direction differ).
//
// ws layout (float offsets, R = CB*2048 rows):
//   lnxb bf16[R][1024] @ 0          (dead after in_proj)
//   xcb  bf16[R][2048] @ R*512      (dead after conv) -> dtbb (softplus dt)
//   zb   bf16[R][2048] @ R*1536
//   xcab bf16[R][2048] @ R*2560
//   dbl  bf16[R][128]  @ R*3584     (0:64 dt_in, 64:80 B, 80:96 C, 96:128 pad)
//   yb   bf16[R][2048] @ R*3648
//   weights @ R*4672 : inwb bf16[4096][1024], outwb bf16[1024][2048],
//                      xpwb bf16[128][2048] (rows 96..127 zeroed), dtwb bf16[2048][64]
// CB=4 total 166.5 MB (identical to r7-r9 layout); CB=1 total 51.6 MB.
// out (d_out) doubles as the up/down accumulator: out = x, then += up, += down.

typedef __attribute__((ext_vector_type(8))) short bf16x8;
typedef __attribute__((ext_vector_type(4))) float f32x4;

__device__ __forceinline__ float softplusf(float v) {
    return fmaxf(v, 0.0f) + log1pf(expf(-fabsf(v)));
}
__device__ __forceinline__ float siluf(float v) {
    return v / (1.0f + expf(-v));
}
__device__ __forceinline__ unsigned short f2bf(float f) {
    unsigned u = __float_as_uint(f);
    unsigned r = u + 0x7FFFu + ((u >> 16) & 1u);   // RNE
    return (unsigned short)(r >> 16);
}
__device__ __forceinline__ float bf2f(unsigned short u) {
    return __uint_as_float(((unsigned)u) << 16);
}

// ---------------- f32 -> bf16 conversion ----------------
__global__ __launch_bounds__(256) void tob16_kernel(
    const float* __restrict__ in, unsigned short* __restrict__ out, int n4)
{
    const int i = blockIdx.x * 256 + threadIdx.x;
    if (i >= n4) return;
    const float4 v = reinterpret_cast<const float4*>(in)[i];
    ushort4 s;
    s.x = f2bf(v.x); s.y = f2bf(v.y); s.z = f2bf(v.z); s.w = f2bf(v.w);
    reinterpret_cast<ushort4*>(out)[i] = s;
}

// x_proj_w [96][2048] f32 -> bf16 [128][2048], rows 96..127 zeroed
__global__ __launch_bounds__(256) void pad_xpw_kernel(
    const float* __restrict__ in, unsigned short* __restrict__ out)
{
    const int i = blockIdx.x * 256 + threadIdx.x;   // ushort4 index, 65536 total
    if (i >= 65536) return;
    const int row = (i * 4) >> 11;                  // 2048 cols per row
    ushort4 s = make_ushort4(0, 0, 0, 0);
    if (row < 96) {
        const float4 v = reinterpret_cast<const float4*>(in)[i];
        s.x = f2bf(v.x); s.y = f2bf(v.y); s.z = f2bf(v.z); s.w = f2bf(v.w);
    }
    reinterpret_cast<ushort4*>(out)[i] = s;
}

// ---------------- out = x (residual base; up/down accumulate into it later) ----------------
__global__ __launch_bounds__(256) void copyx_kernel(
    const float* __restrict__ x, float* __restrict__ out)
{
    const size_t i = (size_t)blockIdx.x * 256 + threadIdx.x;  // float4 index
    reinterpret_cast<float4*>(out)[i] = reinterpret_cast<const float4*>(x)[i];
}

// ---------------- LayerNorm (one param set per call) -> bf16 ----------------
__global__ __launch_bounds__(256) void ln_kernel(
    const float* __restrict__ x,
    const float* __restrict__ g, const float* __restrict__ b,
    unsigned short* __restrict__ lnxb)
{
    const int row = blockIdx.x;            // chunk-local row
    const int tid = threadIdx.x;
    const float4 v = reinterpret_cast<const float4*>(x + (size_t)row * DM)[tid];
    float s  = v.x + v.y + v.z + v.w;
    float ss = v.x*v.x + v.y*v.y + v.z*v.z + v.w*v.w;
    #pragma unroll
    for (int off = 32; off >= 1; off >>= 1) {
        s  += __shfl_xor(s,  off, 64);
        ss += __shfl_xor(ss, off, 64);
    }
    __shared__ float sb[8];
    const int lane = tid & 63, w = tid >> 6;
    if (lane == 0) { sb[w] = s; sb[4 + w] = ss; }
    __syncthreads();
    s  = sb[0] + sb[1] + sb[2] + sb[3];
    ss = sb[4] + sb[5] + sb[6] + sb[7];
    const float mean = s * (1.0f / DM);
    const float var  = ss * (1.0f / DM) - mean * mean;
    const float rstd = rsqrtf(var + 1e-5f);

    const float4 G = reinterpret_cast<const float4*>(g)[tid];
    const float4 B = reinterpret_cast<const float4*>(b)[tid];
    ushort4 o;
    o.x = f2bf((v.x - mean) * rstd * G.x + B.x);
    o.y = f2bf((v.y - mean) * rstd * G.y + B.y);
    o.z = f2bf((v.z - mean) * rstd * G.z + B.z);
    o.w = f2bf((v.w - mean) * rstd * G.w + B.w);
    reinterpret_cast<ushort4*>(lnxb + (size_t)row * DM)[tid] = o;
}

// ---------------- bf16 MFMA GEMM: C[M,N] = act(A[M,K]*B[N,K]^T + bias) ----------------
// 128x128 tile, BK=64, 4 waves (2x2 of 64x64), mfma_f32_16x16x32_bf16.
// Register-staged LDS fill (plain loads + ds_write_b128; no global_load_lds — crash hedge).
// M,N mult of 128; K mult of 64; lda/ldb mult of 8; grid mult of 8.
// outmode: 0 = f32 store, 1 = bf16 store, 2 = f32 accumulate (C += result).
__global__ __launch_bounds__(256) void gemm_bf16_nt(
    const unsigned short* __restrict__ A, const unsigned short* __restrict__ B,
    void* __restrict__ C, int M, int N, int K, int lda, int ldb, int ldc,
    const float* __restrict__ bias, int act, int outmode)
{
    __shared__ __align__(16) unsigned short Al[128 * 64];
    __shared__ __align__(16) unsigned short Bl[128 * 64];

    int bid = blockIdx.x;
    const int nwg = gridDim.x;
    bid = (bid & 7) * (nwg >> 3) + (bid >> 3);   // XCD-aware swizzle (nwg % 8 == 0)
    const int nbm = M >> 7;
    const int bn = bid / nbm, bm = bid % nbm;    // consecutive bids share the B panel
    const int m0 = bm << 7, n0 = bn << 7;

    const int tid  = threadIdx.x;
    const int w    = tid >> 6, lane = tid & 63;
    const int wr   = w >> 1,  wc   = w & 1;      // wave -> 64x64 quadrant
    const int lrow = lane >> 3;                  // staging: 0..7
    const int lcol = (lane & 7) * 8;             // staging: element offset in k
    const int fr   = lane & 15, fq = lane >> 4;  // fragment lane decomposition

    f32x4 acc[4][4] = {};

    for (int k0 = 0; k0 < K; k0 += 64) {
        // issue global loads early (overlap previous iteration's MFMA tail)
        bf16x8 ar[4], br[4];
        #pragma unroll
        for (int q = 0; q < 4; ++q) {
            const int r = w * 32 + q * 8 + lrow;
            ar[q] = *reinterpret_cast<const bf16x8*>(A + (size_t)(m0 + r) * lda + (k0 + lcol));
            br[q] = *reinterpret_cast<const bf16x8*>(B + (size_t)(n0 + r) * ldb + (k0 + lcol));
        }
        __syncthreads();   // previous iteration's LDS readers done
        #pragma unroll
        for (int q = 0; q < 4; ++q) {
            const int r = w * 32 + q * 8 + lrow;
            *reinterpret_cast<bf16x8*>(&Al[r * 64 + lcol]) = ar[q];   // 2-way bank alias: free
            *reinterpret_cast<bf16x8*>(&Bl[r * 64 + lcol]) = br[q];
        }
        __syncthreads();   // tiles visible

        #pragma unroll
        for (int ks = 0; ks < 2; ++ks) {
            bf16x8 af[4], bg[4];
            #pragma unroll
            for (int i = 0; i < 4; ++i)
                af[i] = *reinterpret_cast<const bf16x8*>(
                    &Al[(wr * 64 + i * 16 + fr) * 64 + ks * 32 + fq * 8]);
            #pragma unroll
            for (int j = 0; j < 4; ++j)
                bg[j] = *reinterpret_cast<const bf16x8*>(
                    &Bl[(wc * 64 + j * 16 + fr) * 64 + ks * 32 + fq * 8]);
            #pragma unroll
            for (int i = 0; i < 4; ++i)
                #pragma unroll
                for (int j = 0; j < 4; ++j)
                    acc[i][j] = __builtin_amdgcn_mfma_f32_16x16x32_bf16(
                        af[i], bg[j], acc[i][j], 0, 0, 0);
        }
    }

    // C/D layout (m89-verified): col = lane&15, row = (lane>>4)*4 + reg
    const int col0 = n0 + wc * 64;
    #pragma unroll
    for (int j = 0; j < 4; ++j) {
        const int col = col0 + j * 16 + fr;
        const float bj = bias ? bias[col] : 0.f;
        #pragma unroll
        for (int i = 0; i < 4; ++i) {
            const int row0 = m0 + wr * 64 + i * 16 + fq * 4;
            #pragma unroll
            for (int r = 0; r < 4; ++r) {
                float v = acc[i][j][r] + bj;
                if (act == 1) v = softplusf(v);
                const size_t idx = (size_t)(row0 + r) * ldc + col;
                if (outmode == 1)
                    ((unsigned short*)C)[idx] = f2bf(v);
                else if (outmode == 2)
                    ((float*)C)[idx] += v;
                else
                    ((float*)C)[idx] = v;
            }
        }
    }
}

// ---------------- depthwise causal conv1d (direction-aware) + SiLU, bf16 in/out ----------------
// p==0: out[l] = cb + cw3*x[l] + cw2*x[l-1] + cw1*x[l-2] + cw0*x[l-3]
// p==1: taps at l, l+1, l+2, l+3 (reverse pass in unflipped coords)
// grid = nb*64 blocks (nb = batches in chunk)
__global__ __launch_bounds__(256) void conv_silu_kernel(
    const unsigned short* __restrict__ xcb, const float* __restrict__ cw,
    const float* __restrict__ cb, unsigned short* __restrict__ xcab, int p)
{
    const int t  = blockIdx.x;           // nb*64 blocks: b * 8dchunk * 8lchunk
    const int lc = t & 7;
    const int dc = (t >> 3) & 7;
    const int b  = t >> 6;
    const int d  = dc * 256 + threadIdx.x;
    const size_t R = (size_t)b * LSEQ;

    const float w0 = cw[d * 4 + 0], w1 = cw[d * 4 + 1];
    const float w2 = cw[d * 4 + 2], w3 = cw[d * 4 + 3];
    const float bconv = cb[d];

#define XC(l) bf2f(xcb[(R + (size_t)(l)) * DI + d])
    if (p == 0) {
        const int l0 = lc * 256;
        float r1 = (l0 - 1 >= 0) ? XC(l0 - 1) : 0.f;
        float r2 = (l0 - 2 >= 0) ? XC(l0 - 2) : 0.f;
        float r3 = (l0 - 3 >= 0) ? XC(l0 - 3) : 0.f;
        for (int l = l0; l < l0 + 256; ++l) {
            const float r0 = XC(l);
            const float o = siluf(bconv + w3 * r0 + w2 * r1 + w1 * r2 + w0 * r3);
            xcab[(R + (size_t)l) * DI + d] = f2bf(o);
            r3 = r2; r2 = r1; r1 = r0;
        }
    } else {
        const int lh = lc * 256 + 255;
        float r1 = (lh + 1 < LSEQ) ? XC(lh + 1) : 0.f;
        float r2 = (lh + 2 < LSEQ) ? XC(lh + 2) : 0.f;
        float r3 = (lh + 3 < LSEQ) ? XC(lh + 3) : 0.f;
        for (int l = lh; l >= lc * 256; --l) {
            const float r0 = XC(l);
            const float o = siluf(bconv + w3 * r0 + w2 * r1 + w1 * r2 + w0 * r3);
            xcab[(R + (size_t)l) * DI + d] = f2bf(o);
            r3 = r2; r2 = r1; r1 = r0;
        }
    }
#undef XC
}

// ---------------- selective scan + D skip + z-gate -> bf16 y ----------------
// grid = nb*128 blocks
__global__ __launch_bounds__(256) void scan_kernel(
    const unsigned short* __restrict__ dtbb, const unsigned short* __restrict__ xcab,
    const unsigned short* __restrict__ dbl, const unsigned short* __restrict__ zb,
    const float* __restrict__ alog, const float* __restrict__ Dp,
    unsigned short* __restrict__ yb, int p)
{
    const int t    = blockIdx.x;          // nb*128 blocks: b * 128dblk
    const int dblk = t & 127;
    const int b    = t >> 7;
    const int tid  = threadIdx.x;
    const int n    = tid & 15;
    const int dl   = tid >> 4;
    const int d    = dblk * 16 + dl;
    const size_t R = (size_t)b * LSEQ;

    const float Adn = -expf(alog[(size_t)d * NSTATE + n]);
    const float Dd  = Dp[d];

    float h = 0.f;
    int l = (p == 0) ? 0 : (LSEQ - 1);
    const int step = (p == 0) ? 1 : -1;

    for (int it = 0; it < LSEQ; ++it, l += step) {
        const size_t m = R + (size_t)l;
        const float dtv = bf2f(dtbb[m * DI + d]);
        const float xv  = bf2f(xcab[m * DI + d]);
        const float Bv  = bf2f(dbl[m * 128 + 64 + n]);
        const float Cv  = bf2f(dbl[m * 128 + 80 + n]);
        h = h * expf(dtv * Adn) + (dtv * xv) * Bv;
        float part = h * Cv;
        part += __shfl_xor(part, 1, 16);
        part += __shfl_xor(part, 2, 16);
        part += __shfl_xor(part, 4, 16);
        part += __shfl_xor(part, 8, 16);
        if (n == 0) {
            const float zv = bf2f(zb[m * DI + d]);
            const float y  = part + Dd * xv;
            yb[m * DI + d] = f2bf(y * siluf(zv));
        }
    }
}

extern "C" void kernel_launch(void* const* d_in, const int* in_sizes, int n_in,
                              void* d_out, int out_size, void* d_ws, size_t ws_size,
                              hipStream_t stream)
{
    (void)in_sizes; (void)n_in; (void)out_size;
    const float* x      = (const float*)d_in[0];
    const float* g1     = (const float*)d_in[1];
    const float* b1     = (const float*)d_in[2];
    const float* g2     = (const float*)d_in[3];
    const float* b2     = (const float*)d_in[4];
    const float* inw    = (const float*)d_in[5];   // [4096,1024]
    const float* cw     = (const float*)d_in[6];   // [2048,4]
    const float* cbias  = (const float*)d_in[7];   // [2048]
    const float* xpw    = (const float*)d_in[8];   // [96,2048]
    const float* dtw    = (const float*)d_in[9];   // [2048,64]
    const float* dtbias = (const float*)d_in[10];  // [2048]
    const float* alog   = (const float*)d_in[11];  // [2048,16]
    const float* Dp     = (const float*)d_in[12];  // [2048]
    const float* outw   = (const float*)d_in[13];  // [1024,2048]
    float* out = (float*)d_out;

    // Adaptive chunking on ws_size (constant per run -> identical launch sequence
    // every call -> graph-capture safe). CB=4: 166.5 MB; CB=1: 51.6 MB.
    const int CB = (ws_size >= 41615360ull * 4ull) ? 4 : 1;
    const size_t R = (size_t)CB * 2048;   // rows per chunk
    const int M = CB * 2048;

    float* ws = (float*)d_ws;
    unsigned short* lnxb  = (unsigned short*)ws;
    unsigned short* xcb   = (unsigned short*)(ws + R * 512);
    unsigned short* dtbb  = xcb;                               // overlay (xcb dead after conv)
    unsigned short* zb    = (unsigned short*)(ws + R * 1536);
    unsigned short* xcab  = (unsigned short*)(ws + R * 2560);
    unsigned short* dbl   = (unsigned short*)(ws + R * 3584);
    unsigned short* yb    = (unsigned short*)(ws + R * 3648);
    float* wbase = ws + R * 4672;
    unsigned short* inwb  = (unsigned short*)wbase;
    unsigned short* outwb = (unsigned short*)(wbase + 2097152);
    unsigned short* xpwb  = (unsigned short*)(wbase + 3145728);
    unsigned short* dtwb  = (unsigned short*)(wbase + 3276800);

    // 0. weight conversion f32 -> bf16 (once per launch)
    tob16_kernel<<<4096, 256, 0, stream>>>(inw,  inwb,  1048576);  // 4096*1024/4
    tob16_kernel<<<2048, 256, 0, stream>>>(outw, outwb, 524288);   // 1024*2048/4
    tob16_kernel<<<128,  256, 0, stream>>>(dtw,  dtwb,  32768);    // 2048*64/4
    pad_xpw_kernel<<<256, 256, 0, stream>>>(xpw, xpwb);

    // 1. out = x (up/down accumulate into it)
    copyx_kernel<<<8192, 256, 0, stream>>>(x, out);

    // 2. directional passes x batch chunks, sequential, sharing all buffers
    for (int p = 0; p < 2; ++p) {
        const float* g = p ? g2 : g1;
        const float* b = p ? b2 : b1;
        for (int b0 = 0; b0 < 4; b0 += CB) {
            const float* xch = x   + (size_t)b0 * LSEQ * DM;
            float*       och = out + (size_t)b0 * LSEQ * DM;

            ln_kernel<<<M, 256, 0, stream>>>(xch, g, b, lnxb);

            // in_proj as two GEMMs: xc = lnx @ W[0:2048]^T, z = lnx @ W[2048:4096]^T
            gemm_bf16_nt<<<CB * 256, 256, 0, stream>>>(lnxb, inwb, xcb,
                M, 2048, 1024, 1024, 1024, 2048, nullptr, 0, 1);
            gemm_bf16_nt<<<CB * 256, 256, 0, stream>>>(lnxb, inwb + (size_t)2048 * 1024, zb,
                M, 2048, 1024, 1024, 1024, 2048, nullptr, 0, 1);

            // depthwise conv + SiLU (direction-aware)
            conv_silu_kernel<<<CB * 64, 256, 0, stream>>>(xcb, cw, cbias, xcab, p);

            // x_proj (padded N=128): dbl = xca @ x_proj_w^T
            gemm_bf16_nt<<<CB * 16, 256, 0, stream>>>(xcab, xpwb, dbl,
                M, 128, 2048, 2048, 2048, 128, nullptr, 0, 1);

            // dt: dtbb = softplus(dbl[:, :64] @ dt_proj_w^T + dt_proj_b)  (overlays xcb)
            gemm_bf16_nt<<<CB * 256, 256, 0, stream>>>(dbl, dtwb, dtbb,
                M, 2048, 64, 128, 64, 2048, dtbias, 1, 1);

            // selective scan (direction-aware) + D skip + z gate
            scan_kernel<<<CB * 128, 256, 0, stream>>>(dtbb, xcab, dbl, zb, alog, Dp, yb, p);

            // out_proj: out_chunk += y @ out_proj_w^T (accumulate epilogue)
            gemm_bf16_nt<<<CB * 128, 256, 0, stream>>>(yb, outwb, och,
                M, 1024, 2048, 2048, 2048, 1024, nullptr, 0, 2);
        }
    }
}